// Round 2
// baseline (343.883 us; speedup 1.0000x reference)
//
#include <hip/hip_runtime.h>

// TreeCRF inside pass, L=32 channels, perfect binary tree (heap layout).
// parent[i] = em[i] + LSE_j(T[i,j]+left[j]) + LSE_j(T[i,j]+right[j])
// LSE_j(T[i,j]+c[j]) = m + log(sum_j E[i,j]*exp(c[j]-m)),  E=exp(T), m=max_j c[j].
//
// Kernel A: 512 blocks; each block takes 256 contiguous leaves and fuses the
// bottom 8 levels in LDS, emitting one row of the width-512 level.
// Kernel B: 1 block; takes those 512 rows and fuses the top 9 levels to root.

__device__ __forceinline__ void lse_matvec(const float* __restrict__ ET,
                                           float* x /*in: scores, out: pairsum*/,
                                           float m)
{
    // x[j] = exp(x[j]-m) ; y = E^T-broadcast matvec ; x[i] = m+log(y[i]) + partner
#pragma unroll
    for (int j = 0; j < 32; ++j) x[j] = __expf(x[j] - m);
    float y[32];
#pragma unroll
    for (int i = 0; i < 32; ++i) y[i] = 0.0f;
#pragma unroll
    for (int j = 0; j < 32; ++j) {
        float cv = x[j];
        const float4* er = (const float4*)(ET + j * 32);   // wave-uniform b128
#pragma unroll
        for (int k = 0; k < 8; ++k) {
            float4 e = er[k];
            y[4 * k + 0] = fmaf(e.x, cv, y[4 * k + 0]);
            y[4 * k + 1] = fmaf(e.y, cv, y[4 * k + 1]);
            y[4 * k + 2] = fmaf(e.z, cv, y[4 * k + 2]);
            y[4 * k + 3] = fmaf(e.w, cv, y[4 * k + 3]);
        }
    }
#pragma unroll
    for (int i = 0; i < 32; ++i) {
        float cb = m + __logf(y[i]);
        x[i] = cb + __shfl_xor(cb, 1);   // sibling child is partner lane
    }
}

__global__ __launch_bounds__(256) void treecrf_fuse8(
    const float* __restrict__ em,      // [262143][32]
    const float* __restrict__ trans,   // [32][32]
    float* __restrict__ out512)        // [512][32]
{
    __shared__ float ET[1024];         // ET[j*32+i] = exp(trans[i*32+j])
    __shared__ float S[128 * 33];      // parent rows, stride 33 (2-way only)
    int t = threadIdx.x;
#pragma unroll
    for (int r = 0; r < 4; ++r) {
        int idx = t + r * 256;
        int j = idx >> 5, i = idx & 31;
        ET[idx] = __expf(trans[i * 32 + j]);
    }
    int b = blockIdx.x;

    float x[32];
    {   // leaves: nodes 131071 + 256*b + t
        const float4* xr = (const float4*)(em + (size_t)(131071 + 256 * b + t) * 32);
#pragma unroll
        for (int k = 0; k < 8; ++k) {
            float4 v = xr[k];
            x[4 * k + 0] = v.x; x[4 * k + 1] = v.y;
            x[4 * k + 2] = v.z; x[4 * k + 3] = v.w;
        }
    }
    __syncthreads();                   // ET ready

    int nc = 256;
    for (int s = 0; s < 8; ++s) {
        if (s > 0) {
            if (t < nc) {
#pragma unroll
                for (int j = 0; j < 32; ++j) x[j] = S[t * 33 + j];
            }
            __syncthreads();           // reads done before parents overwrite
        }
        if (t < nc) {
            float m = x[0];
#pragma unroll
            for (int j = 1; j < 32; ++j) m = fmaxf(m, x[j]);
            lse_matvec(ET, x, m);
            int p = t >> 1, h = t & 1;
            int Wp = 65536 >> s;                      // parent level width
            size_t node = (size_t)(Wp - 1) + (size_t)(nc >> 1) * b + p;
            const float* emr = em + node * 32 + h * 16;
            if (s == 7) {
                float* o = out512 + (size_t)b * 32 + h * 16;
#pragma unroll
                for (int k = 0; k < 16; ++k) o[k] = emr[k] + x[h * 16 + k];
            } else {
                float* dr = S + p * 33 + h * 16;
#pragma unroll
                for (int k = 0; k < 16; ++k) dr[k] = emr[k] + x[h * 16 + k];
            }
        }
        __syncthreads();
        nc >>= 1;
    }
}

__global__ __launch_bounds__(256) void treecrf_tail9(
    const float* __restrict__ child0,  // [512][32] (width-512 level scores)
    const float* __restrict__ em,
    const float* __restrict__ trans,
    float* __restrict__ out_root)      // [32]
{
    __shared__ float ET[1024];
    __shared__ float A[256 * 33];
    __shared__ float B[128 * 33];
    int t = threadIdx.x;
    for (int idx = t; idx < 1024; idx += 256) {
        int j = idx >> 5, i = idx & 31;
        ET[idx] = __expf(trans[i * 32 + j]);
    }
    __syncthreads();

    int nc = 512;
    for (int l = 0; l < 9; ++l) {
        const float* src = (l & 1) ? A : B;           // l=0 unused (global)
        float* dst = (l & 1) ? B : A;
        for (int base = 0; base < nc; base += 256) {
            int q = base + t;
            if (q < nc) {
                float x[32];
                if (l == 0) {
                    const float4* xr = (const float4*)(child0 + (size_t)q * 32);
#pragma unroll
                    for (int k = 0; k < 8; ++k) {
                        float4 v = xr[k];
                        x[4 * k + 0] = v.x; x[4 * k + 1] = v.y;
                        x[4 * k + 2] = v.z; x[4 * k + 3] = v.w;
                    }
                } else {
#pragma unroll
                    for (int j = 0; j < 32; ++j) x[j] = src[q * 33 + j];
                }
                float m = x[0];
#pragma unroll
                for (int j = 1; j < 32; ++j) m = fmaxf(m, x[j]);
                lse_matvec(ET, x, m);
                int p = q >> 1, h = q & 1;
                size_t node = (size_t)(nc >> 1) - 1 + p;
                const float* emr = em + node * 32 + h * 16;
                if (nc == 2) {
#pragma unroll
                    for (int k = 0; k < 16; ++k)
                        out_root[h * 16 + k] = emr[k] + x[h * 16 + k];
                } else {
                    float* dr = dst + p * 33 + h * 16;
#pragma unroll
                    for (int k = 0; k < 16; ++k) dr[k] = emr[k] + x[h * 16 + k];
                }
            }
        }
        __syncthreads();
        nc >>= 1;
    }
}

extern "C" void kernel_launch(void* const* d_in, const int* in_sizes, int n_in,
                              void* d_out, int out_size, void* d_ws, size_t ws_size,
                              hipStream_t stream)
{
    const float* em = (const float*)d_in[0];
    const float* trans = (const float*)d_in[1];
    float* out512 = (float*)d_ws;               // 512*32 floats = 64 KB

    treecrf_fuse8<<<dim3(512), dim3(256), 0, stream>>>(em, trans, out512);
    treecrf_tail9<<<dim3(1), dim3(256), 0, stream>>>(out512, em, trans,
                                                     (float*)d_out);
}

// Round 3
// 221.629 us; speedup vs baseline: 1.5516x; 1.5516x over previous
//
#include <hip/hip_runtime.h>

// TreeCRF inside pass, L=32 channels, perfect binary tree (heap layout).
// parent[i] = em[i] + LSE_j(T[i,j]+left[j]) + LSE_j(T[i,j]+right[j])
// LSE_j(T[i,j]+c[j]) = m + log(sum_j E[i,j]*exp(c[j]-m)),  E=exp(T), m=max_j c[j].
//
// Kernel A (unchanged from R2): 512 blocks; each block takes 256 contiguous
// leaves, fuses the bottom 8 levels in LDS, emits one row of the width-512
// level. Kernel B (rewritten): 1 block x 1024 threads; 9 levels 512->root,
// two-phase (child,channel)/(parent,channel) mapping, E rows in registers.

__device__ __forceinline__ void lse_matvec(const float* __restrict__ ET,
                                           float* x, float m)
{
#pragma unroll
    for (int j = 0; j < 32; ++j) x[j] = __expf(x[j] - m);
    float y[32];
#pragma unroll
    for (int i = 0; i < 32; ++i) y[i] = 0.0f;
#pragma unroll
    for (int j = 0; j < 32; ++j) {
        float cv = x[j];
        const float4* er = (const float4*)(ET + j * 32);   // wave-uniform b128
#pragma unroll
        for (int k = 0; k < 8; ++k) {
            float4 e = er[k];
            y[4 * k + 0] = fmaf(e.x, cv, y[4 * k + 0]);
            y[4 * k + 1] = fmaf(e.y, cv, y[4 * k + 1]);
            y[4 * k + 2] = fmaf(e.z, cv, y[4 * k + 2]);
            y[4 * k + 3] = fmaf(e.w, cv, y[4 * k + 3]);
        }
    }
#pragma unroll
    for (int i = 0; i < 32; ++i) {
        float cb = m + __logf(y[i]);
        x[i] = cb + __shfl_xor(cb, 1);   // sibling child is partner lane
    }
}

__global__ __launch_bounds__(256) void treecrf_fuse8(
    const float* __restrict__ em,      // [262143][32]
    const float* __restrict__ trans,   // [32][32]
    float* __restrict__ out512)        // [512][32]
{
    __shared__ float ET[1024];         // ET[j*32+i] = exp(trans[i*32+j])
    __shared__ float S[128 * 33];
    int t = threadIdx.x;
#pragma unroll
    for (int r = 0; r < 4; ++r) {
        int idx = t + r * 256;
        int j = idx >> 5, i = idx & 31;
        ET[idx] = __expf(trans[i * 32 + j]);
    }
    int b = blockIdx.x;

    float x[32];
    {
        const float4* xr = (const float4*)(em + (size_t)(131071 + 256 * b + t) * 32);
#pragma unroll
        for (int k = 0; k < 8; ++k) {
            float4 v = xr[k];
            x[4 * k + 0] = v.x; x[4 * k + 1] = v.y;
            x[4 * k + 2] = v.z; x[4 * k + 3] = v.w;
        }
    }
    __syncthreads();

    int nc = 256;
    for (int s = 0; s < 8; ++s) {
        if (s > 0) {
            if (t < nc) {
#pragma unroll
                for (int j = 0; j < 32; ++j) x[j] = S[t * 33 + j];
            }
            __syncthreads();
        }
        if (t < nc) {
            float m = x[0];
#pragma unroll
            for (int j = 1; j < 32; ++j) m = fmaxf(m, x[j]);
            lse_matvec(ET, x, m);
            int p = t >> 1, h = t & 1;
            int Wp = 65536 >> s;
            size_t node = (size_t)(Wp - 1) + (size_t)(nc >> 1) * b + p;
            const float* emr = em + node * 32 + h * 16;
            if (s == 7) {
                float* o = out512 + (size_t)b * 32 + h * 16;
#pragma unroll
                for (int k = 0; k < 16; ++k) o[k] = emr[k] + x[h * 16 + k];
            } else {
                float* dr = S + p * 33 + h * 16;
#pragma unroll
                for (int k = 0; k < 16; ++k) dr[k] = emr[k] + x[h * 16 + k];
            }
        }
        __syncthreads();
        nc >>= 1;
    }
}

// ---- Tail: 1 block x 1024 threads, levels 512 -> 1 --------------------------
// Per level: phase1 (child,channel): butterfly max over 32-lane group,
// store exp(x-m) row into C (chunked, 128 children max) + M.
// phase2 (parent,channel): sl/sr = dot(E[i,:], C-rows) with E row in regs,
// score = em + ml + log(sl) + mr + log(sr), written in-place into S.
#define TSTRIDE 36

__global__ __launch_bounds__(1024) void treecrf_tail(
    const float* __restrict__ g512,    // [512][32]
    const float* __restrict__ em,
    const float* __restrict__ trans,
    float* __restrict__ out_root)      // [32]
{
    __shared__ float S[256 * TSTRIDE]; // scores, in-place shrink
    __shared__ float C[128 * TSTRIDE]; // exp rows of current chunk
    __shared__ float M[128];           // chunk-local row maxes
    int t = threadIdx.x;
    int lane_i = t & 31;

    // E row for this lane's channel, in registers
    float er[32];
    {
        const float4* tr = (const float4*)(trans + lane_i * 32);
#pragma unroll
        for (int k = 0; k < 8; ++k) {
            float4 v = tr[k];
            er[4 * k + 0] = __expf(v.x);
            er[4 * k + 1] = __expf(v.y);
            er[4 * k + 2] = __expf(v.z);
            er[4 * k + 3] = __expf(v.w);
        }
    }

    int nc = 512;
    for (int l = 0; l < 9; ++l) {
        int nchunks = (nc + 127) / 128;
        int cs = (nc < 128) ? nc : 128;            // children per chunk
        for (int c = 0; c < nchunks; ++c) {
            // ---- phase 1 ----
            for (int idx = t; idx < cs * 32; idx += 1024) {
                int ql = idx >> 5, j = idx & 31;
                int q = c * 128 + ql;
                float x = (l == 0) ? g512[q * 32 + j] : S[q * TSTRIDE + j];
                float m = x;
                m = fmaxf(m, __shfl_xor(m, 16));
                m = fmaxf(m, __shfl_xor(m, 8));
                m = fmaxf(m, __shfl_xor(m, 4));
                m = fmaxf(m, __shfl_xor(m, 2));
                m = fmaxf(m, __shfl_xor(m, 1));
                C[ql * TSTRIDE + j] = __expf(x - m);
                if (j == 0) M[ql] = m;
            }
            __syncthreads();
            // ---- phase 2 ----
            int np = cs >> 1;                       // parents this chunk
            for (int idx = t; idx < np * 32; idx += 1024) {
                int pl = idx >> 5, i = idx & 31;
                int p = c * 64 + pl;
                const float* cl = C + (2 * pl) * TSTRIDE;
                const float* cr = C + (2 * pl + 1) * TSTRIDE;
                float sl = 0.0f, sr = 0.0f;
#pragma unroll
                for (int j = 0; j < 32; ++j) {
                    sl = fmaf(er[j], cl[j], sl);
                    sr = fmaf(er[j], cr[j], sr);
                }
                size_t node = (size_t)(nc >> 1) - 1 + p;
                float val = em[node * 32 + i]
                          + M[2 * pl] + __logf(sl)
                          + M[2 * pl + 1] + __logf(sr);
                if (nc == 2) out_root[i] = val;
                else S[p * TSTRIDE + i] = val;
            }
            __syncthreads();
        }
        nc >>= 1;
    }
}

extern "C" void kernel_launch(void* const* d_in, const int* in_sizes, int n_in,
                              void* d_out, int out_size, void* d_ws, size_t ws_size,
                              hipStream_t stream)
{
    const float* em = (const float*)d_in[0];
    const float* trans = (const float*)d_in[1];
    float* out512 = (float*)d_ws;               // 512*32 floats = 64 KB

    treecrf_fuse8<<<dim3(512), dim3(256), 0, stream>>>(em, trans, out512);
    treecrf_tail<<<dim3(1), dim3(1024), 0, stream>>>(out512, em, trans,
                                                     (float*)d_out);
}

// Round 4
// 121.209 us; speedup vs baseline: 2.8371x; 1.8285x over previous
//
#include <hip/hip_runtime.h>

// TreeCRF inside pass, L=32 channels, perfect binary tree (heap layout).
// parent[i] = em[i] + LSE_j(T[i,j]+left[j]) + LSE_j(T[i,j]+right[j])
// LSE_j(T[i,j]+c[j]) = m + log(sum_j E[i,j]*exp(c[j]-m)), E=exp(T), m=max_j c[j].
//
// Two-phase mapping per level (keeps ALL waves busy at every level):
//  phase1 (child, f4-chunk): row max via 8-lane shfl butterfly, exp row -> C
//  phase2 (parent, channel): E row in registers, 16 b128 broadcast reads of
//                            exp rows, 128 FMA, 2 logs, write parent row -> S
// Stride-32 LDS rows: every pattern here is uniform-broadcast or <=2-way bank
// aliasing (free on gfx950), so no padding and b128 stays aligned.

__device__ __forceinline__ void run_subtree(
    const int NT, const int t, const int levels, int Wp /*first parent width*/,
    const int b,                        // block offset (0 for the top kernel)
    const float* __restrict__ gchild,   // [2^levels][32] first-level child rows
    const float* __restrict__ em,
    const float* __restrict__ erow,     // [32] exp(trans[t&31, :]) in registers
    float* __restrict__ S,              // [2^(levels-1)][32]
    float* __restrict__ C,              // [128][32]
    float* __restrict__ M,              // [128]
    float* __restrict__ gout)           // [32] output row
{
    int nc = 1 << levels;
    for (int l = 0; l < levels; ++l) {
        int nchunks = (nc + 127) >> 7;
        int cs = nc < 128 ? nc : 128;
        for (int c = 0; c < nchunks; ++c) {
            // ---- phase 1: exp rows + maxes ----
            for (int u = t; u < cs * 8; u += NT) {
                int ql = u >> 3, k = u & 7;
                int q = (c << 7) + ql;
                const float4* src = (l == 0)
                    ? (const float4*)(gchild + (size_t)q * 32)
                    : (const float4*)(S + q * 32);
                float4 x = src[k];
                float4 r = x;
#define MSTEP(mask) { float4 o; o.x=__shfl_xor(r.x,mask); o.y=__shfl_xor(r.y,mask); \
                      o.z=__shfl_xor(r.z,mask); o.w=__shfl_xor(r.w,mask); \
                      r.x=fmaxf(r.x,o.x); r.y=fmaxf(r.y,o.y); \
                      r.z=fmaxf(r.z,o.z); r.w=fmaxf(r.w,o.w); }
                MSTEP(1) MSTEP(2) MSTEP(4)
#undef MSTEP
                float m = fmaxf(fmaxf(r.x, r.y), fmaxf(r.z, r.w));
                float4 e;
                e.x = __expf(x.x - m); e.y = __expf(x.y - m);
                e.z = __expf(x.z - m); e.w = __expf(x.w - m);
                ((float4*)(C + ql * 32))[k] = e;
                if (k == 0) M[ql] = m;
            }
            __syncthreads();
            // ---- phase 2: parent scores ----
            int np = cs >> 1;
            for (int u = t; u < np * 32; u += NT) {
                int pl = u >> 5, i = u & 31;
                int p = (c << 6) + pl;
                const float4* cl = (const float4*)(C + (2 * pl) * 32);
                const float4* cr = (const float4*)(C + (2 * pl + 1) * 32);
                float sl = 0.0f, sr = 0.0f;
#pragma unroll
                for (int k = 0; k < 8; ++k) {
                    float4 a = cl[k], d = cr[k];
                    sl = fmaf(erow[4 * k + 0], a.x, sl);
                    sl = fmaf(erow[4 * k + 1], a.y, sl);
                    sl = fmaf(erow[4 * k + 2], a.z, sl);
                    sl = fmaf(erow[4 * k + 3], a.w, sl);
                    sr = fmaf(erow[4 * k + 0], d.x, sr);
                    sr = fmaf(erow[4 * k + 1], d.y, sr);
                    sr = fmaf(erow[4 * k + 2], d.z, sr);
                    sr = fmaf(erow[4 * k + 3], d.w, sr);
                }
                size_t node = (size_t)(Wp - 1) + (size_t)(Wp >> 9) * b + p;
                float val = em[node * 32 + i]
                          + M[2 * pl] + __logf(sl)
                          + M[2 * pl + 1] + __logf(sr);
                if (l == levels - 1) gout[i] = val;
                else S[p * 32 + i] = val;
            }
            __syncthreads();
        }
        nc >>= 1; Wp >>= 1;
    }
}

__device__ __forceinline__ void load_erow(const float* __restrict__ trans,
                                          int lane_i, float* erow)
{
    const float4* tr = (const float4*)(trans + lane_i * 32);
#pragma unroll
    for (int k = 0; k < 8; ++k) {
        float4 v = tr[k];
        erow[4 * k + 0] = __expf(v.x);
        erow[4 * k + 1] = __expf(v.y);
        erow[4 * k + 2] = __expf(v.z);
        erow[4 * k + 3] = __expf(v.w);
    }
}

// Kernel A: 512 blocks x 256 thr; 256 contiguous leaves -> one width-512 row.
__global__ __launch_bounds__(256) void treecrf_bottom(
    const float* __restrict__ em, const float* __restrict__ trans,
    float* __restrict__ out512, int n_leaves)
{
    __shared__ float S[128 * 32];
    __shared__ float C[128 * 32];
    __shared__ float M[128];
    int t = threadIdx.x, b = blockIdx.x;
    float erow[32];
    load_erow(trans, t & 31, erow);
    run_subtree(256, t, 8, n_leaves >> 1, b,
                em + (size_t)(n_leaves - 1 + 256 * b) * 32, em, erow,
                S, C, M, out512 + (size_t)b * 32);
}

// Kernel B: 1 block x 1024 thr; 512 width-512 rows -> root.
__global__ __launch_bounds__(1024) void treecrf_top(
    const float* __restrict__ g512, const float* __restrict__ em,
    const float* __restrict__ trans, float* __restrict__ out_root)
{
    __shared__ float S[256 * 32];
    __shared__ float C[128 * 32];
    __shared__ float M[128];
    int t = threadIdx.x;
    float erow[32];
    load_erow(trans, t & 31, erow);
    run_subtree(1024, t, 9, 256, 0, g512, em, erow, S, C, M, out_root);
}

extern "C" void kernel_launch(void* const* d_in, const int* in_sizes, int n_in,
                              void* d_out, int out_size, void* d_ws, size_t ws_size,
                              hipStream_t stream)
{
    const float* em = (const float*)d_in[0];
    const float* trans = (const float*)d_in[1];
    int n_nodes = in_sizes[0] / 32;          // 262143
    int n_leaves = (n_nodes + 1) / 2;        // 131072
    int blocksA = n_leaves / 256;            // 512

    float* out512 = (float*)d_ws;            // 512*32 floats
    treecrf_bottom<<<dim3(blocksA), dim3(256), 0, stream>>>(em, trans, out512,
                                                            n_leaves);
    treecrf_top<<<dim3(1), dim3(1024), 0, stream>>>(out512, em, trans,
                                                    (float*)d_out);
}

// Round 5
// 112.911 us; speedup vs baseline: 3.0456x; 1.0735x over previous
//
#include <hip/hip_runtime.h>

// TreeCRF inside pass, L=32 channels, perfect binary tree (heap layout).
// parent[i] = em[i] + LSE_j(T[i,j]+left[j]) + LSE_j(T[i,j]+right[j])
// LSE_j(T[i,j]+c[j]) = m + log(sum_j E[i,j]*exp(c[j]-m)), E=exp(T), m=max_j c[j].
//
// Two-phase mapping per level (keeps ALL waves busy at every level):
//  phase1 (child, f4-chunk): row max via 8-lane shfl butterfly, exp row -> C
//  phase2 (parent, channel): E row in registers, 16 b128 broadcast reads of
//                            exp rows, 128 FMA, 2 logs, write parent row -> S
// R5 split: bottom = 256 blocks x 1024 thr (1 block/CU, 4 waves/SIMD),
// 512 leaves -> 1 row each (9 levels). top = 1 block x 1024 thr, 8 levels,
// chunk-free (C holds all 256 child rows).

template <int NT, int CROWS>
__device__ __forceinline__ void run_levels(
    const int t, const int levels, int Wp, int boff, const int b,
    const float* __restrict__ gchild,   // [2^levels][32] first-level children
    const float* __restrict__ em,
    const float* __restrict__ erow,     // exp(trans[t&31, :]) in registers
    float* __restrict__ S,              // [2^(levels-1)][32] in-place shrink
    float* __restrict__ C,              // [CROWS][32]
    float* __restrict__ M,              // [CROWS]
    float* __restrict__ gout)           // [32]
{
    int nc = 1 << levels;
    for (int l = 0; l < levels; ++l) {
        int nchunks = (nc + CROWS - 1) / CROWS;
        int cs = nc < CROWS ? nc : CROWS;
        for (int c = 0; c < nchunks; ++c) {
            // ---- phase 1: exp rows + maxes ----
            for (int u = t; u < cs * 8; u += NT) {
                int ql = u >> 3, k = u & 7;
                int q = c * CROWS + ql;
                const float4* src = (l == 0)
                    ? (const float4*)(gchild + (size_t)q * 32)
                    : (const float4*)(S + q * 32);
                float4 x = src[k];
                float4 r = x;
#define MSTEP(mask) { float4 o; o.x=__shfl_xor(r.x,mask); o.y=__shfl_xor(r.y,mask); \
                      o.z=__shfl_xor(r.z,mask); o.w=__shfl_xor(r.w,mask); \
                      r.x=fmaxf(r.x,o.x); r.y=fmaxf(r.y,o.y); \
                      r.z=fmaxf(r.z,o.z); r.w=fmaxf(r.w,o.w); }
                MSTEP(1) MSTEP(2) MSTEP(4)
#undef MSTEP
                float m = fmaxf(fmaxf(r.x, r.y), fmaxf(r.z, r.w));
                float4 e;
                e.x = __expf(x.x - m); e.y = __expf(x.y - m);
                e.z = __expf(x.z - m); e.w = __expf(x.w - m);
                ((float4*)(C + ql * 32))[k] = e;
                if (k == 0) M[ql] = m;
            }
            __syncthreads();
            // ---- phase 2: parent scores ----
            int np = cs >> 1;
            for (int u = t; u < np * 32; u += NT) {
                int pl = u >> 5, i = u & 31;
                int p = c * (CROWS / 2) + pl;
                const float4* cl = (const float4*)(C + (2 * pl) * 32);
                const float4* cr = (const float4*)(C + (2 * pl + 1) * 32);
                float sl = 0.0f, sr = 0.0f;
#pragma unroll
                for (int k = 0; k < 8; ++k) {
                    float4 a = cl[k], d = cr[k];
                    sl = fmaf(erow[4 * k + 0], a.x, sl);
                    sl = fmaf(erow[4 * k + 1], a.y, sl);
                    sl = fmaf(erow[4 * k + 2], a.z, sl);
                    sl = fmaf(erow[4 * k + 3], a.w, sl);
                    sr = fmaf(erow[4 * k + 0], d.x, sr);
                    sr = fmaf(erow[4 * k + 1], d.y, sr);
                    sr = fmaf(erow[4 * k + 2], d.z, sr);
                    sr = fmaf(erow[4 * k + 3], d.w, sr);
                }
                int node = (Wp - 1) + boff * b + p;
                float val = em[(size_t)node * 32 + i]
                          + M[2 * pl] + __logf(sl)
                          + M[2 * pl + 1] + __logf(sr);
                if (l == levels - 1) gout[i] = val;
                else S[p * 32 + i] = val;
            }
            __syncthreads();
        }
        nc >>= 1; Wp >>= 1; boff >>= 1;
    }
}

__device__ __forceinline__ void load_erow(const float* __restrict__ trans,
                                          int lane_i, float* erow)
{
    const float4* tr = (const float4*)(trans + lane_i * 32);
#pragma unroll
    for (int k = 0; k < 8; ++k) {
        float4 v = tr[k];
        erow[4 * k + 0] = __expf(v.x);
        erow[4 * k + 1] = __expf(v.y);
        erow[4 * k + 2] = __expf(v.z);
        erow[4 * k + 3] = __expf(v.w);
    }
}

// Bottom: 256 blocks x 1024 thr; 512 contiguous leaves -> one width-256 row.
__global__ __launch_bounds__(1024) void treecrf_bottom(
    const float* __restrict__ em, const float* __restrict__ trans,
    float* __restrict__ out256, int n_leaves)
{
    __shared__ float S[256 * 32];      // 32 KB
    __shared__ float C[128 * 32];      // 16 KB
    __shared__ float M[128];
    int t = threadIdx.x, b = blockIdx.x;
    float erow[32];
    load_erow(trans, t & 31, erow);
    run_levels<1024, 128>(t, 9, n_leaves >> 1, 256, b,
                          em + (size_t)(n_leaves - 1 + 512 * b) * 32, em, erow,
                          S, C, M, out256 + (size_t)b * 32);
}

// Top: 1 block x 1024 thr; 256 width-256 rows -> root, chunk-free.
__global__ __launch_bounds__(1024) void treecrf_top(
    const float* __restrict__ g256, const float* __restrict__ em,
    const float* __restrict__ trans, float* __restrict__ out_root)
{
    __shared__ float S[128 * 32];      // 16 KB
    __shared__ float C[256 * 32];      // 32 KB
    __shared__ float M[256];
    int t = threadIdx.x;
    float erow[32];
    load_erow(trans, t & 31, erow);
    run_levels<1024, 256>(t, 8, 128, 0, 0, g256, em, erow, S, C, M, out_root);
}

extern "C" void kernel_launch(void* const* d_in, const int* in_sizes, int n_in,
                              void* d_out, int out_size, void* d_ws, size_t ws_size,
                              hipStream_t stream)
{
    const float* em = (const float*)d_in[0];
    const float* trans = (const float*)d_in[1];
    int n_nodes = in_sizes[0] / 32;          // 262143
    int n_leaves = (n_nodes + 1) / 2;        // 131072
    int blocksA = n_leaves / 512;            // 256

    float* out256 = (float*)d_ws;            // 256*32 floats
    treecrf_bottom<<<dim3(blocksA), dim3(1024), 0, stream>>>(em, trans, out256,
                                                             n_leaves);
    treecrf_top<<<dim3(1), dim3(1024), 0, stream>>>(out256, em, trans,
                                                    (float*)d_out);
}